// Round 1
// baseline (621.523 us; speedup 1.0000x reference)
//
#include <hip/hip_runtime.h>

// PointConv fused pipeline:
//  1. histogram e_query -> cnt
//  2. exclusive scan -> offs, cursors
//  3. fill: scatter e_ref into CSR order (ref_sorted)
//  4. accum: one wave per query; sum ref_feat rows + ref xyz sums
//  5. gemm: qf = (accF@Wm^T + posdiff@Wp^T + cnt*(bm+bp)) / max(cnt,1)
//  6. stats: per-channel sum/sumsq
//  7. bnprep: scale/shift
//  8. bnapply: in-place normalize + ReLU

__global__ void k_count(const int* __restrict__ eq, int* __restrict__ cnt, int E_) {
  int i = blockIdx.x * blockDim.x + threadIdx.x;
  if (i < E_) atomicAdd(&cnt[eq[i]], 1);
}

__global__ __launch_bounds__(1024) void k_scan(const int* __restrict__ cnt, int* __restrict__ offs,
                                               int* __restrict__ cursors, int m) {
  __shared__ int part[1024];
  int t = threadIdx.x;
  int chunk = (m + 1023) >> 10;
  int b = t * chunk;
  int e = b + chunk; if (e > m) e = m;
  int s = 0;
  if (b < m) for (int i = b; i < e; ++i) s += cnt[i];
  part[t] = s;
  __syncthreads();
  for (int off = 1; off < 1024; off <<= 1) {
    int v = 0;
    if (t >= off) v = part[t - off];
    __syncthreads();
    if (t >= off) part[t] += v;
    __syncthreads();
  }
  int run = part[t] - s;  // exclusive prefix
  if (b < m) {
    for (int i = b; i < e; ++i) { offs[i] = run; cursors[i] = run; run += cnt[i]; }
  }
  if (t == 1023) offs[m] = part[1023];
}

__global__ void k_fill(const int* __restrict__ eq, const int* __restrict__ er,
                       int* __restrict__ cursors, int* __restrict__ ref_sorted, int E_) {
  int i = blockIdx.x * blockDim.x + threadIdx.x;
  if (i < E_) {
    int q = eq[i];
    int pos = atomicAdd(&cursors[q], 1);
    ref_sorted[pos] = er[i];
  }
}

// one wave (64 lanes) per query; each lane owns channels {lane, lane+64}
__global__ __launch_bounds__(256) void k_accum(const int* __restrict__ offs,
                                               const int* __restrict__ rs,
                                               const float* __restrict__ feat,
                                               const float* __restrict__ bxyz,
                                               float* __restrict__ accF,
                                               float* __restrict__ possum, int M_) {
  int w = blockIdx.x * 4 + (threadIdx.x >> 6);
  int lane = threadIdx.x & 63;
  if (w >= M_) return;
  int beg = offs[w], end = offs[w + 1];
  float a0 = 0.f, a1 = 0.f, p = 0.f;
  int j = beg;
  for (; j + 4 <= end; j += 4) {
    int r0 = rs[j], r1 = rs[j + 1], r2 = rs[j + 2], r3 = rs[j + 3];
    a0 += feat[r0 * 128 + lane];       a1 += feat[r0 * 128 + 64 + lane];
    a0 += feat[r1 * 128 + lane];       a1 += feat[r1 * 128 + 64 + lane];
    a0 += feat[r2 * 128 + lane];       a1 += feat[r2 * 128 + 64 + lane];
    a0 += feat[r3 * 128 + lane];       a1 += feat[r3 * 128 + 64 + lane];
    if (lane < 3)
      p += bxyz[r0 * 4 + 1 + lane] + bxyz[r1 * 4 + 1 + lane] +
           bxyz[r2 * 4 + 1 + lane] + bxyz[r3 * 4 + 1 + lane];
  }
  for (; j < end; ++j) {
    int r = rs[j];
    a0 += feat[r * 128 + lane];
    a1 += feat[r * 128 + 64 + lane];
    if (lane < 3) p += bxyz[r * 4 + 1 + lane];
  }
  accF[w * 128 + lane] = a0;
  accF[w * 128 + 64 + lane] = a1;
  if (lane < 3) possum[w * 4 + lane] = p;   // sums of ref xyz (dims 1..3)
}

// 32 queries x 128 channels per block; 4x4 register microtile per thread.
__global__ __launch_bounds__(256) void k_gemm(
    const float* __restrict__ accF, const int* __restrict__ offs,
    const float* __restrict__ possum, const float* __restrict__ qxyz,
    const float* __restrict__ Wm, const float* __restrict__ Wp,
    const float* __restrict__ bm, const float* __restrict__ bp,
    float* __restrict__ out, int M_) {
  __shared__ float sA[32 * 132];   // accF tile [32][128], stride 132
  __shared__ float sW[128 * 36];   // W k-tile [128][32], stride 36
  int t = threadIdx.x;
  int q0 = blockIdx.x * 32;
  // stage accF tile (coalesced float4)
  #pragma unroll
  for (int i = 0; i < 4; ++i) {
    int f = t + 256 * i;
    int q = f >> 5;
    int kk = (f & 31) << 2;
    float4 v = make_float4(0.f, 0.f, 0.f, 0.f);
    if (q0 + q < M_) v = *(const float4*)&accF[(q0 + q) * 128 + kk];
    *(float4*)&sA[q * 132 + kk] = v;
  }
  float acc[4][4];
  #pragma unroll
  for (int i = 0; i < 4; ++i)
    #pragma unroll
    for (int j = 0; j < 4; ++j) acc[i][j] = 0.f;
  int q0l = (t >> 5) << 2;  // 0,4,...,28
  int cb = t & 31;          // channel base; thread's channels = cb + 32j
  for (int kt = 0; kt < 4; ++kt) {
    __syncthreads();
    #pragma unroll
    for (int i = 0; i < 4; ++i) {     // stage W[:, kt*32 .. kt*32+31]
      int f = t + 256 * i;
      int c = f >> 3;
      int kk = (f & 7) << 2;
      float4 v = *(const float4*)&Wm[c * 128 + kt * 32 + kk];
      *(float4*)&sW[c * 36 + kk] = v;
    }
    __syncthreads();
    #pragma unroll
    for (int kk4 = 0; kk4 < 8; ++kk4) {
      float4 av[4], wv[4];
      #pragma unroll
      for (int i = 0; i < 4; ++i)
        av[i] = *(const float4*)&sA[(q0l + i) * 132 + kt * 32 + (kk4 << 2)];
      #pragma unroll
      for (int j = 0; j < 4; ++j)
        wv[j] = *(const float4*)&sW[(cb + 32 * j) * 36 + (kk4 << 2)];
      #pragma unroll
      for (int i = 0; i < 4; ++i)
        #pragma unroll
        for (int j = 0; j < 4; ++j) {
          acc[i][j] = fmaf(av[i].x, wv[j].x, acc[i][j]);
          acc[i][j] = fmaf(av[i].y, wv[j].y, acc[i][j]);
          acc[i][j] = fmaf(av[i].z, wv[j].z, acc[i][j]);
          acc[i][j] = fmaf(av[i].w, wv[j].w, acc[i][j]);
        }
    }
  }
  float fcnt[4], inv[4], dx[4], dy[4], dz[4];
  #pragma unroll
  for (int i = 0; i < 4; ++i) {
    int q = q0 + q0l + i;
    if (q < M_) {
      int o0 = offs[q], o1 = offs[q + 1];
      float fc = (float)(o1 - o0);
      fcnt[i] = fc;
      inv[i] = 1.f / fmaxf(fc, 1.f);
      dx[i] = possum[q * 4 + 0] - fc * qxyz[q * 4 + 1];
      dy[i] = possum[q * 4 + 1] - fc * qxyz[q * 4 + 2];
      dz[i] = possum[q * 4 + 2] - fc * qxyz[q * 4 + 3];
    } else {
      fcnt[i] = 0.f; inv[i] = 1.f; dx[i] = dy[i] = dz[i] = 0.f;
    }
  }
  #pragma unroll
  for (int j = 0; j < 4; ++j) {
    int c = cb + 32 * j;
    float w0 = Wp[c * 3 + 0], w1 = Wp[c * 3 + 1], w2 = Wp[c * 3 + 2];
    float bb = bm[c] + bp[c];
    #pragma unroll
    for (int i = 0; i < 4; ++i) {
      int q = q0 + q0l + i;
      if (q < M_) {
        float v = acc[i][j] + dx[i] * w0 + dy[i] * w1 + dz[i] * w2 + fcnt[i] * bb;
        out[q * 128 + c] = v * inv[i];
      }
    }
  }
}

__global__ __launch_bounds__(256) void k_stats(const float* __restrict__ qf,
                                               float* __restrict__ stats, int M_) {
  __shared__ float ls[256], ls2[256];
  int c = threadIdx.x & 127;
  int half = threadIdx.x >> 7;
  int rpb = (M_ + gridDim.x - 1) / gridDim.x;
  int r0 = blockIdx.x * rpb;
  int r1 = r0 + rpb; if (r1 > M_) r1 = M_;
  float s = 0.f, s2 = 0.f;
  for (int r = r0 + half; r < r1; r += 2) {
    float v = qf[r * 128 + c];
    s += v; s2 += v * v;
  }
  ls[threadIdx.x] = s; ls2[threadIdx.x] = s2;
  __syncthreads();
  if (half == 0) {
    s += ls[threadIdx.x + 128];
    s2 += ls2[threadIdx.x + 128];
    atomicAdd(&stats[c], s);
    atomicAdd(&stats[128 + c], s2);
  }
}

__global__ void k_bnprep(float* __restrict__ stats, const float* __restrict__ gamma,
                         const float* __restrict__ beta, int M_) {
  int c = threadIdx.x;
  float inv_m = 1.f / (float)M_;
  float mu = stats[c] * inv_m;
  float var = stats[128 + c] * inv_m - mu * mu;
  var = fmaxf(var, 0.f);
  float sc = gamma[c] * rsqrtf(var + 1e-5f);
  stats[256 + c] = sc;
  stats[384 + c] = beta[c] - mu * sc;
}

__global__ __launch_bounds__(256) void k_bnapply(float* __restrict__ out,
                                                 const float* __restrict__ stats, int total4) {
  const float4* sc4 = (const float4*)(stats + 256);
  const float4* sh4 = (const float4*)(stats + 384);
  float4* o4 = (float4*)out;
  for (int i = blockIdx.x * blockDim.x + threadIdx.x; i < total4;
       i += gridDim.x * blockDim.x) {
    float4 v = o4[i];
    float4 s = sc4[i & 31];
    float4 h = sh4[i & 31];
    v.x = fmaxf(fmaf(v.x, s.x, h.x), 0.f);
    v.y = fmaxf(fmaf(v.y, s.y, h.y), 0.f);
    v.z = fmaxf(fmaf(v.z, s.z, h.z), 0.f);
    v.w = fmaxf(fmaf(v.w, s.w, h.w), 0.f);
    o4[i] = v;
  }
}

static inline size_t align256(size_t x) { return (x + 255) & ~(size_t)255; }

extern "C" void kernel_launch(void* const* d_in, const int* in_sizes, int n_in,
                              void* d_out, int out_size, void* d_ws, size_t ws_size,
                              hipStream_t stream) {
  const float* ref_bxyz  = (const float*)d_in[0];
  const float* ref_feat  = (const float*)d_in[1];
  const float* query_bxyz = (const float*)d_in[2];
  const int*   e_ref     = (const int*)d_in[3];
  const int*   e_query   = (const int*)d_in[4];
  const float* W_pos     = (const float*)d_in[5];
  // d_in[6] = b_pos
  const float* b_pos     = (const float*)d_in[6];
  const float* W_mlp     = (const float*)d_in[7];
  const float* b_mlp     = (const float*)d_in[8];
  const float* gamma     = (const float*)d_in[9];
  const float* beta      = (const float*)d_in[10];

  int M_ = in_sizes[2] / 4;
  int E_ = in_sizes[3];

  char* ws = (char*)d_ws;
  size_t off = 0;
  int* cnt        = (int*)(ws + off); off += align256((size_t)M_ * 4);
  int* offs       = (int*)(ws + off); off += align256((size_t)(M_ + 1) * 4);
  int* cursors    = (int*)(ws + off); off += align256((size_t)M_ * 4);
  int* ref_sorted = (int*)(ws + off); off += align256((size_t)E_ * 4);
  float* possum   = (float*)(ws + off); off += align256((size_t)M_ * 4 * 4);
  float* accF     = (float*)(ws + off); off += align256((size_t)M_ * 128 * 4);
  float* stats    = (float*)(ws + off); off += align256(4 * 128 * 4);

  hipMemsetAsync(cnt, 0, (size_t)M_ * 4, stream);
  hipMemsetAsync(stats, 0, 2 * 128 * 4, stream);

  float* out = (float*)d_out;

  k_count<<<(E_ + 255) / 256, 256, 0, stream>>>(e_query, cnt, E_);
  k_scan<<<1, 1024, 0, stream>>>(cnt, offs, cursors, M_);
  k_fill<<<(E_ + 255) / 256, 256, 0, stream>>>(e_query, e_ref, cursors, ref_sorted, E_);
  k_accum<<<(M_ + 3) / 4, 256, 0, stream>>>(offs, ref_sorted, ref_feat, ref_bxyz,
                                            accF, possum, M_);
  k_gemm<<<(M_ + 31) / 32, 256, 0, stream>>>(accF, offs, possum, query_bxyz,
                                             W_mlp, W_pos, b_mlp, b_pos, out, M_);
  k_stats<<<256, 256, 0, stream>>>(out, stats, M_);
  k_bnprep<<<1, 128, 0, stream>>>(stats, gamma, beta, M_);
  k_bnapply<<<2048, 256, 0, stream>>>(out, stats, M_ * 32);
}

// Round 2
// 430.883 us; speedup vs baseline: 1.4424x; 1.4424x over previous
//
#include <hip/hip_runtime.h>

// PointConv fused pipeline (linked-list edition):
//  1. build: per-query linked list via atomicExch on head[] (L2-resident),
//            node[i] = {next, e_ref[i]} written coalesced
//  2. accum: half-wave (32 lanes) per query chases its list, float4 gather of
//            feat rows; stores accF (sum of rows), possum.xyz (sum ref xyz),
//            possum.w (edge count)
//  3. gemm:  qf = (accF@Wm^T + posdiff@Wp^T + cnt*(bm+bp)) / max(cnt,1)
//  4. stats: per-channel sum/sumsq
//  5. bnprep: scale/shift
//  6. bnapply: in-place normalize + ReLU

__global__ void k_build(const int* __restrict__ eq, const int* __restrict__ er,
                        int* __restrict__ head, int2* __restrict__ node, int E_) {
  int i = blockIdx.x * blockDim.x + threadIdx.x;
  if (i < E_) {
    int q = eq[i];
    int prev = atomicExch(&head[q], i);
    node[i] = make_int2(prev, er[i]);
  }
}

// half-wave (32 lanes) per query; lane l owns channels 4l..4l+3 (one float4)
__global__ __launch_bounds__(256) void k_accum(const int* __restrict__ head,
                                               const int2* __restrict__ node,
                                               const float4* __restrict__ feat4,
                                               const float* __restrict__ bxyz,
                                               float4* __restrict__ accF4,
                                               float* __restrict__ possum, int M_) {
  int q = blockIdx.x * 8 + (threadIdx.x >> 5);
  int l = threadIdx.x & 31;
  if (q >= M_) return;
  int i = head[q];
  float4 a = make_float4(0.f, 0.f, 0.f, 0.f);
  float p = 0.f, c = 0.f;
  while (i >= 0) {
    int2 nd = node[i];          // {next, ref}
    int r = nd.y;
    float4 v = feat4[(size_t)r * 32 + l];
    a.x += v.x; a.y += v.y; a.z += v.z; a.w += v.w;
    if (l < 3) p += bxyz[r * 4 + 1 + l];
    c += 1.f;
    i = nd.x;
  }
  accF4[(size_t)q * 32 + l] = a;
  if (l < 3) possum[q * 4 + l] = p;
  if (l == 3) possum[q * 4 + 3] = c;
}

// 32 queries x 128 channels per block; 4x4 register microtile per thread.
__global__ __launch_bounds__(256) void k_gemm(
    const float* __restrict__ accF, const float4* __restrict__ possum4,
    const float* __restrict__ qxyz,
    const float* __restrict__ Wm, const float* __restrict__ Wp,
    const float* __restrict__ bm, const float* __restrict__ bp,
    float* __restrict__ out, int M_) {
  __shared__ float sA[32 * 132];   // accF tile [32][128], stride 132
  __shared__ float sW[128 * 36];   // W k-tile [128][32], stride 36
  int t = threadIdx.x;
  int q0 = blockIdx.x * 32;
  #pragma unroll
  for (int i = 0; i < 4; ++i) {
    int f = t + 256 * i;
    int q = f >> 5;
    int kk = (f & 31) << 2;
    float4 v = make_float4(0.f, 0.f, 0.f, 0.f);
    if (q0 + q < M_) v = *(const float4*)&accF[(q0 + q) * 128 + kk];
    *(float4*)&sA[q * 132 + kk] = v;
  }
  float acc[4][4];
  #pragma unroll
  for (int i = 0; i < 4; ++i)
    #pragma unroll
    for (int j = 0; j < 4; ++j) acc[i][j] = 0.f;
  int q0l = (t >> 5) << 2;  // 0,4,...,28
  int cb = t & 31;          // channel base; thread's channels = cb + 32j
  for (int kt = 0; kt < 4; ++kt) {
    __syncthreads();
    #pragma unroll
    for (int i = 0; i < 4; ++i) {     // stage W[:, kt*32 .. kt*32+31]
      int f = t + 256 * i;
      int c = f >> 3;
      int kk = (f & 7) << 2;
      float4 v = *(const float4*)&Wm[c * 128 + kt * 32 + kk];
      *(float4*)&sW[c * 36 + kk] = v;
    }
    __syncthreads();
    #pragma unroll
    for (int kk4 = 0; kk4 < 8; ++kk4) {
      float4 av[4], wv[4];
      #pragma unroll
      for (int i = 0; i < 4; ++i)
        av[i] = *(const float4*)&sA[(q0l + i) * 132 + kt * 32 + (kk4 << 2)];
      #pragma unroll
      for (int j = 0; j < 4; ++j)
        wv[j] = *(const float4*)&sW[(cb + 32 * j) * 36 + (kk4 << 2)];
      #pragma unroll
      for (int i = 0; i < 4; ++i)
        #pragma unroll
        for (int j = 0; j < 4; ++j) {
          acc[i][j] = fmaf(av[i].x, wv[j].x, acc[i][j]);
          acc[i][j] = fmaf(av[i].y, wv[j].y, acc[i][j]);
          acc[i][j] = fmaf(av[i].z, wv[j].z, acc[i][j]);
          acc[i][j] = fmaf(av[i].w, wv[j].w, acc[i][j]);
        }
    }
  }
  float fcnt[4], inv[4], dx[4], dy[4], dz[4];
  #pragma unroll
  for (int i = 0; i < 4; ++i) {
    int q = q0 + q0l + i;
    if (q < M_) {
      float4 ps = possum4[q];
      float fc = ps.w;
      fcnt[i] = fc;
      inv[i] = 1.f / fmaxf(fc, 1.f);
      dx[i] = ps.x - fc * qxyz[q * 4 + 1];
      dy[i] = ps.y - fc * qxyz[q * 4 + 2];
      dz[i] = ps.z - fc * qxyz[q * 4 + 3];
    } else {
      fcnt[i] = 0.f; inv[i] = 1.f; dx[i] = dy[i] = dz[i] = 0.f;
    }
  }
  #pragma unroll
  for (int j = 0; j < 4; ++j) {
    int c = cb + 32 * j;
    float w0 = Wp[c * 3 + 0], w1 = Wp[c * 3 + 1], w2 = Wp[c * 3 + 2];
    float bb = bm[c] + bp[c];
    #pragma unroll
    for (int i = 0; i < 4; ++i) {
      int q = q0 + q0l + i;
      if (q < M_) {
        float v = acc[i][j] + dx[i] * w0 + dy[i] * w1 + dz[i] * w2 + fcnt[i] * bb;
        out[q * 128 + c] = v * inv[i];
      }
    }
  }
}

__global__ __launch_bounds__(256) void k_stats(const float* __restrict__ qf,
                                               float* __restrict__ stats, int M_) {
  __shared__ float ls[256], ls2[256];
  int c = threadIdx.x & 127;
  int half = threadIdx.x >> 7;
  int rpb = (M_ + gridDim.x - 1) / gridDim.x;
  int r0 = blockIdx.x * rpb;
  int r1 = r0 + rpb; if (r1 > M_) r1 = M_;
  float s = 0.f, s2 = 0.f;
  for (int r = r0 + half; r < r1; r += 2) {
    float v = qf[r * 128 + c];
    s += v; s2 += v * v;
  }
  ls[threadIdx.x] = s; ls2[threadIdx.x] = s2;
  __syncthreads();
  if (half == 0) {
    s += ls[threadIdx.x + 128];
    s2 += ls2[threadIdx.x + 128];
    atomicAdd(&stats[c], s);
    atomicAdd(&stats[128 + c], s2);
  }
}

__global__ void k_bnprep(float* __restrict__ stats, const float* __restrict__ gamma,
                         const float* __restrict__ beta, int M_) {
  int c = threadIdx.x;
  float inv_m = 1.f / (float)M_;
  float mu = stats[c] * inv_m;
  float var = stats[128 + c] * inv_m - mu * mu;
  var = fmaxf(var, 0.f);
  float sc = gamma[c] * rsqrtf(var + 1e-5f);
  stats[256 + c] = sc;
  stats[384 + c] = beta[c] - mu * sc;
}

__global__ __launch_bounds__(256) void k_bnapply(float* __restrict__ out,
                                                 const float* __restrict__ stats, int total4) {
  const float4* sc4 = (const float4*)(stats + 256);
  const float4* sh4 = (const float4*)(stats + 384);
  float4* o4 = (float4*)out;
  for (int i = blockIdx.x * blockDim.x + threadIdx.x; i < total4;
       i += gridDim.x * blockDim.x) {
    float4 v = o4[i];
    float4 s = sc4[i & 31];
    float4 h = sh4[i & 31];
    v.x = fmaxf(fmaf(v.x, s.x, h.x), 0.f);
    v.y = fmaxf(fmaf(v.y, s.y, h.y), 0.f);
    v.z = fmaxf(fmaf(v.z, s.z, h.z), 0.f);
    v.w = fmaxf(fmaf(v.w, s.w, h.w), 0.f);
    o4[i] = v;
  }
}

static inline size_t align256(size_t x) { return (x + 255) & ~(size_t)255; }

extern "C" void kernel_launch(void* const* d_in, const int* in_sizes, int n_in,
                              void* d_out, int out_size, void* d_ws, size_t ws_size,
                              hipStream_t stream) {
  const float* ref_bxyz   = (const float*)d_in[0];
  const float* ref_feat   = (const float*)d_in[1];
  const float* query_bxyz = (const float*)d_in[2];
  const int*   e_ref      = (const int*)d_in[3];
  const int*   e_query    = (const int*)d_in[4];
  const float* W_pos      = (const float*)d_in[5];
  const float* b_pos      = (const float*)d_in[6];
  const float* W_mlp      = (const float*)d_in[7];
  const float* b_mlp      = (const float*)d_in[8];
  const float* gamma      = (const float*)d_in[9];
  const float* beta       = (const float*)d_in[10];

  int M_ = in_sizes[2] / 4;
  int E_ = in_sizes[3];

  char* ws = (char*)d_ws;
  size_t off = 0;
  int*   head   = (int*)(ws + off);   off += align256((size_t)M_ * 4);
  int2*  node   = (int2*)(ws + off);  off += align256((size_t)E_ * 8);
  float* possum = (float*)(ws + off); off += align256((size_t)M_ * 4 * 4);
  float* accF   = (float*)(ws + off); off += align256((size_t)M_ * 128 * 4);
  float* stats  = (float*)(ws + off); off += align256(4 * 128 * 4);

  hipMemsetAsync(head, 0xFF, (size_t)M_ * 4, stream);     // head[q] = -1
  hipMemsetAsync(stats, 0, 2 * 128 * 4, stream);

  float* out = (float*)d_out;

  k_build<<<(E_ + 255) / 256, 256, 0, stream>>>(e_query, e_ref, head, node, E_);
  k_accum<<<(M_ + 7) / 8, 256, 0, stream>>>(head, node, (const float4*)ref_feat,
                                            ref_bxyz, (float4*)accF, possum, M_);
  k_gemm<<<(M_ + 31) / 32, 256, 0, stream>>>(accF, (const float4*)possum, query_bxyz,
                                             W_mlp, W_pos, b_mlp, b_pos, out, M_);
  k_stats<<<256, 256, 0, stream>>>(out, stats, M_);
  k_bnprep<<<1, 128, 0, stream>>>(stats, gamma, beta, M_);
  k_bnapply<<<2048, 256, 0, stream>>>(out, stats, M_ * 32);
}

// Round 4
// 383.350 us; speedup vs baseline: 1.6213x; 1.1240x over previous
//
#include <hip/hip_runtime.h>

// PointConv fused pipeline (linked-list + bf16 feature table):
//  0. cvt:   ref_feat fp32 -> bf16 table in ws (RNE), halves gather bytes
//  1. build: per-query linked list via atomicExch on head[] (L2-resident)
//  2. accum: 16 lanes per query chase its list; uint4 gather = 8 bf16/lane,
//            fp32 accumulate; also sums ref xyz and edge count
//  3. gemm:  qf = (accF@Wm^T + posdiff@Wp^T + cnt*(bm+bp)) / max(cnt,1)
//  4. stats: per-channel sum/sumsq
//  5. bnprep: scale/shift
//  6. bnapply: in-place normalize + ReLU

__device__ __forceinline__ float bf_lo(unsigned u) {
  union { unsigned u; float f; } c; c.u = u << 16; return c.f;
}
__device__ __forceinline__ float bf_hi(unsigned u) {
  union { unsigned u; float f; } c; c.u = u & 0xFFFF0000u; return c.f;
}
__device__ __forceinline__ unsigned pack_bf(float x, float y) {
  union { float f; unsigned u; } a, b; a.f = x; b.f = y;
  unsigned lo = (a.u + 0x7FFFu + ((a.u >> 16) & 1u)) >> 16;
  unsigned hi = (b.u + 0x7FFFu + ((b.u >> 16) & 1u)) >> 16;
  return lo | (hi << 16);
}

__global__ __launch_bounds__(256) void k_cvt(const float4* __restrict__ in,
                                             uint4* __restrict__ outb, int n8) {
  int i = blockIdx.x * blockDim.x + threadIdx.x;
  if (i < n8) {
    float4 a = in[2 * i], b = in[2 * i + 1];
    uint4 o;
    o.x = pack_bf(a.x, a.y);
    o.y = pack_bf(a.z, a.w);
    o.z = pack_bf(b.x, b.y);
    o.w = pack_bf(b.z, b.w);
    outb[i] = o;
  }
}

__global__ void k_build(const int* __restrict__ eq, const int* __restrict__ er,
                        int* __restrict__ head, int2* __restrict__ node, int E_) {
  int i = blockIdx.x * blockDim.x + threadIdx.x;
  if (i < E_) {
    int q = eq[i];
    int prev = atomicExch(&head[q], i);
    node[i] = make_int2(prev, er[i]);
  }
}

// 16 lanes per query; lane l owns channels 8l..8l+7 (one uint4 = 8 bf16)
__global__ __launch_bounds__(256) void k_accum_b(const int* __restrict__ head,
                                                 const int2* __restrict__ node,
                                                 const uint4* __restrict__ featb,
                                                 const float* __restrict__ bxyz,
                                                 float4* __restrict__ accF4,
                                                 float* __restrict__ possum, int M_) {
  int q = blockIdx.x * 16 + (threadIdx.x >> 4);
  int l = threadIdx.x & 15;
  if (q >= M_) return;
  int i = head[q];
  float a0 = 0.f, a1 = 0.f, a2 = 0.f, a3 = 0.f;
  float a4 = 0.f, a5 = 0.f, a6 = 0.f, a7 = 0.f;
  float p = 0.f, c = 0.f;
  while (i >= 0) {
    int2 nd = node[i];              // {next, ref}
    int r = nd.y;
    uint4 v = featb[(size_t)r * 16 + l];
    a0 += bf_lo(v.x); a1 += bf_hi(v.x);
    a2 += bf_lo(v.y); a3 += bf_hi(v.y);
    a4 += bf_lo(v.z); a5 += bf_hi(v.z);
    a6 += bf_lo(v.w); a7 += bf_hi(v.w);
    if (l < 3) p += bxyz[r * 4 + 1 + l];
    c += 1.f;
    i = nd.x;
  }
  float4 o0 = make_float4(a0, a1, a2, a3);
  float4 o1 = make_float4(a4, a5, a6, a7);
  accF4[(size_t)q * 32 + l * 2] = o0;
  accF4[(size_t)q * 32 + l * 2 + 1] = o1;
  if (l < 3) possum[q * 4 + l] = p;
  if (l == 3) possum[q * 4 + 3] = c;
}

// fallback: 32 lanes per query, fp32 gather (used only if ws too small for bf16 table)
__global__ __launch_bounds__(256) void k_accum(const int* __restrict__ head,
                                               const int2* __restrict__ node,
                                               const float4* __restrict__ feat4,
                                               const float* __restrict__ bxyz,
                                               float4* __restrict__ accF4,
                                               float* __restrict__ possum, int M_) {
  int q = blockIdx.x * 8 + (threadIdx.x >> 5);
  int l = threadIdx.x & 31;
  if (q >= M_) return;
  int i = head[q];
  float4 a = make_float4(0.f, 0.f, 0.f, 0.f);
  float p = 0.f, c = 0.f;
  while (i >= 0) {
    int2 nd = node[i];
    int r = nd.y;
    float4 v = feat4[(size_t)r * 32 + l];
    a.x += v.x; a.y += v.y; a.z += v.z; a.w += v.w;
    if (l < 3) p += bxyz[r * 4 + 1 + l];
    c += 1.f;
    i = nd.x;
  }
  accF4[(size_t)q * 32 + l] = a;
  if (l < 3) possum[q * 4 + l] = p;
  if (l == 3) possum[q * 4 + 3] = c;
}

// 32 queries x 128 channels per block; 4x4 register microtile per thread.
__global__ __launch_bounds__(256) void k_gemm(
    const float* __restrict__ accF, const float4* __restrict__ possum4,
    const float* __restrict__ qxyz,
    const float* __restrict__ Wm, const float* __restrict__ Wp,
    const float* __restrict__ bm, const float* __restrict__ bp,
    float* __restrict__ out, int M_) {
  __shared__ float sA[32 * 132];   // accF tile [32][128], stride 132
  __shared__ float sW[128 * 36];   // W k-tile [128][32], stride 36
  int t = threadIdx.x;
  int q0 = blockIdx.x * 32;
  #pragma unroll
  for (int i = 0; i < 4; ++i) {
    int f = t + 256 * i;
    int q = f >> 5;
    int kk = (f & 31) << 2;
    float4 v = make_float4(0.f, 0.f, 0.f, 0.f);
    if (q0 + q < M_) v = *(const float4*)&accF[(q0 + q) * 128 + kk];
    *(float4*)&sA[q * 132 + kk] = v;
  }
  float acc[4][4];
  #pragma unroll
  for (int i = 0; i < 4; ++i)
    #pragma unroll
    for (int j = 0; j < 4; ++j) acc[i][j] = 0.f;
  int q0l = (t >> 5) << 2;  // 0,4,...,28
  int cb = t & 31;          // channel base; thread's channels = cb + 32j
  for (int kt = 0; kt < 4; ++kt) {
    __syncthreads();
    #pragma unroll
    for (int i = 0; i < 4; ++i) {     // stage W[:, kt*32 .. kt*32+31]
      int f = t + 256 * i;
      int c = f >> 3;
      int kk = (f & 7) << 2;
      float4 v = *(const float4*)&Wm[c * 128 + kt * 32 + kk];
      *(float4*)&sW[c * 36 + kk] = v;
    }
    __syncthreads();
    #pragma unroll
    for (int kk4 = 0; kk4 < 8; ++kk4) {
      float4 av[4], wv[4];
      #pragma unroll
      for (int i = 0; i < 4; ++i)
        av[i] = *(const float4*)&sA[(q0l + i) * 132 + kt * 32 + (kk4 << 2)];
      #pragma unroll
      for (int j = 0; j < 4; ++j)
        wv[j] = *(const float4*)&sW[(cb + 32 * j) * 36 + (kk4 << 2)];
      #pragma unroll
      for (int i = 0; i < 4; ++i)
        #pragma unroll
        for (int j = 0; j < 4; ++j) {
          acc[i][j] = fmaf(av[i].x, wv[j].x, acc[i][j]);
          acc[i][j] = fmaf(av[i].y, wv[j].y, acc[i][j]);
          acc[i][j] = fmaf(av[i].z, wv[j].z, acc[i][j]);
          acc[i][j] = fmaf(av[i].w, wv[j].w, acc[i][j]);
        }
    }
  }
  float fcnt[4], inv[4], dx[4], dy[4], dz[4];
  #pragma unroll
  for (int i = 0; i < 4; ++i) {
    int q = q0 + q0l + i;
    if (q < M_) {
      float4 ps = possum4[q];
      float fc = ps.w;
      fcnt[i] = fc;
      inv[i] = 1.f / fmaxf(fc, 1.f);
      dx[i] = ps.x - fc * qxyz[q * 4 + 1];
      dy[i] = ps.y - fc * qxyz[q * 4 + 2];
      dz[i] = ps.z - fc * qxyz[q * 4 + 3];
    } else {
      fcnt[i] = 0.f; inv[i] = 1.f; dx[i] = dy[i] = dz[i] = 0.f;
    }
  }
  #pragma unroll
  for (int j = 0; j < 4; ++j) {
    int c = cb + 32 * j;
    float w0 = Wp[c * 3 + 0], w1 = Wp[c * 3 + 1], w2 = Wp[c * 3 + 2];
    float bb = bm[c] + bp[c];
    #pragma unroll
    for (int i = 0; i < 4; ++i) {
      int q = q0 + q0l + i;
      if (q < M_) {
        float v = acc[i][j] + dx[i] * w0 + dy[i] * w1 + dz[i] * w2 + fcnt[i] * bb;
        out[q * 128 + c] = v * inv[i];
      }
    }
  }
}

__global__ __launch_bounds__(256) void k_stats(const float* __restrict__ qf,
                                               float* __restrict__ stats, int M_) {
  __shared__ float ls[256], ls2[256];
  int c = threadIdx.x & 127;
  int half = threadIdx.x >> 7;
  int rpb = (M_ + gridDim.x - 1) / gridDim.x;
  int r0 = blockIdx.x * rpb;
  int r1 = r0 + rpb; if (r1 > M_) r1 = M_;
  float s = 0.f, s2 = 0.f;
  for (int r = r0 + half; r < r1; r += 2) {
    float v = qf[r * 128 + c];
    s += v; s2 += v * v;
  }
  ls[threadIdx.x] = s; ls2[threadIdx.x] = s2;
  __syncthreads();
  if (half == 0) {
    s += ls[threadIdx.x + 128];
    s2 += ls2[threadIdx.x + 128];
    atomicAdd(&stats[c], s);
    atomicAdd(&stats[128 + c], s2);
  }
}

__global__ void k_bnprep(float* __restrict__ stats, const float* __restrict__ gamma,
                         const float* __restrict__ beta, int M_) {
  int c = threadIdx.x;
  float inv_m = 1.f / (float)M_;
  float mu = stats[c] * inv_m;
  float var = stats[128 + c] * inv_m - mu * mu;
  var = fmaxf(var, 0.f);
  float sc = gamma[c] * rsqrtf(var + 1e-5f);
  stats[256 + c] = sc;
  stats[384 + c] = beta[c] - mu * sc;
}

__global__ __launch_bounds__(256) void k_bnapply(float* __restrict__ out,
                                                 const float* __restrict__ stats, int total4) {
  const float4* sc4 = (const float4*)(stats + 256);
  const float4* sh4 = (const float4*)(stats + 384);
  float4* o4 = (float4*)out;
  for (int i = blockIdx.x * blockDim.x + threadIdx.x; i < total4;
       i += gridDim.x * blockDim.x) {
    float4 v = o4[i];
    float4 s = sc4[i & 31];
    float4 h = sh4[i & 31];
    v.x = fmaxf(fmaf(v.x, s.x, h.x), 0.f);
    v.y = fmaxf(fmaf(v.y, s.y, h.y), 0.f);
    v.z = fmaxf(fmaf(v.z, s.z, h.z), 0.f);
    v.w = fmaxf(fmaf(v.w, s.w, h.w), 0.f);
    o4[i] = v;
  }
}

static inline size_t align256(size_t x) { return (x + 255) & ~(size_t)255; }

extern "C" void kernel_launch(void* const* d_in, const int* in_sizes, int n_in,
                              void* d_out, int out_size, void* d_ws, size_t ws_size,
                              hipStream_t stream) {
  const float* ref_bxyz   = (const float*)d_in[0];
  const float* ref_feat   = (const float*)d_in[1];
  const float* query_bxyz = (const float*)d_in[2];
  const int*   e_ref      = (const int*)d_in[3];
  const int*   e_query    = (const int*)d_in[4];
  const float* W_pos      = (const float*)d_in[5];
  const float* b_pos      = (const float*)d_in[6];
  const float* W_mlp      = (const float*)d_in[7];
  const float* b_mlp      = (const float*)d_in[8];
  const float* gamma      = (const float*)d_in[9];
  const float* beta       = (const float*)d_in[10];

  int N_ = in_sizes[0] / 4;
  int M_ = in_sizes[2] / 4;
  int E_ = in_sizes[3];

  char* ws = (char*)d_ws;
  size_t off = 0;
  int*   head   = (int*)(ws + off);   off += align256((size_t)M_ * 4);
  int2*  node   = (int2*)(ws + off);  off += align256((size_t)E_ * 8);
  float* possum = (float*)(ws + off); off += align256((size_t)M_ * 4 * 4);
  float* accF   = (float*)(ws + off); off += align256((size_t)M_ * 128 * 4);
  float* stats  = (float*)(ws + off); off += align256(4 * 128 * 4);
  uint4* featb  = (uint4*)(ws + off);
  size_t need_b = off + align256((size_t)N_ * 128 * 2);
  bool use_bf16 = (need_b <= ws_size);

  hipMemsetAsync(head, 0xFF, (size_t)M_ * 4, stream);     // head[q] = -1
  hipMemsetAsync(stats, 0, 2 * 128 * 4, stream);

  float* out = (float*)d_out;

  if (use_bf16) {
    int n8 = N_ * 16;  // groups of 8 floats
    k_cvt<<<(n8 + 255) / 256, 256, 0, stream>>>((const float4*)ref_feat, featb, n8);
  }
  k_build<<<(E_ + 255) / 256, 256, 0, stream>>>(e_query, e_ref, head, node, E_);
  if (use_bf16) {
    k_accum_b<<<(M_ + 15) / 16, 256, 0, stream>>>(head, node, featb, ref_bxyz,
                                                  (float4*)accF, possum, M_);
  } else {
    k_accum<<<(M_ + 7) / 8, 256, 0, stream>>>(head, node, (const float4*)ref_feat,
                                              ref_bxyz, (float4*)accF, possum, M_);
  }
  k_gemm<<<(M_ + 31) / 32, 256, 0, stream>>>(accF, (const float4*)possum, query_bxyz,
                                             W_mlp, W_pos, b_mlp, b_pos, out, M_);
  k_stats<<<256, 256, 0, stream>>>(out, stats, M_);
  k_bnprep<<<1, 128, 0, stream>>>(stats, gamma, beta, M_);
  k_bnapply<<<2048, 256, 0, stream>>>(out, stats, M_ * 32);
}

// Round 5
// 353.087 us; speedup vs baseline: 1.7603x; 1.0857x over previous
//
#include <hip/hip_runtime.h>

// PointConv fused pipeline v3:
//  1. build_cvt: (a) ref_feat fp32 -> bf16 table (RNE, coalesced)
//                (b) per-query linked list via atomicExch on head[]
//  2. accum:     16 lanes/query chase list; uint4 gather = 8 bf16/lane,
//                fp32 accumulate; sums ref xyz and edge count  [CONTROL]
//  3. gemm:      qf = (accF@Wm^T + posdiff@Wp^T + cnt*(bm+bp)) / max(cnt,1)
//                + fused per-channel sum/sumsq partials -> stats atomics
//  4. bnapply:   inline scale/shift from stats, normalize + ReLU in-place

__device__ __forceinline__ float bf_lo(unsigned u) {
  union { unsigned u; float f; } c; c.u = u << 16; return c.f;
}
__device__ __forceinline__ float bf_hi(unsigned u) {
  union { unsigned u; float f; } c; c.u = u & 0xFFFF0000u; return c.f;
}
__device__ __forceinline__ unsigned pack_bf(float x, float y) {
  union { float f; unsigned u; } a, b; a.f = x; b.f = y;
  unsigned lo = (a.u + 0x7FFFu + ((a.u >> 16) & 1u)) >> 16;
  unsigned hi = (b.u + 0x7FFFu + ((b.u >> 16) & 1u)) >> 16;
  return lo | (hi << 16);
}

// fused: bf16 conversion (i < n8) + linked-list build (i < E_)
__global__ __launch_bounds__(256) void k_build_cvt(
    const int* __restrict__ eq, const int* __restrict__ er,
    int* __restrict__ head, int2* __restrict__ node,
    const float4* __restrict__ featf, uint4* __restrict__ featb,
    int E_, int n8) {
  int i = blockIdx.x * blockDim.x + threadIdx.x;
  if (i < n8) {
    float4 a = featf[2 * i], b = featf[2 * i + 1];
    uint4 o;
    o.x = pack_bf(a.x, a.y);
    o.y = pack_bf(a.z, a.w);
    o.z = pack_bf(b.x, b.y);
    o.w = pack_bf(b.z, b.w);
    featb[i] = o;
  }
  if (i < E_) {
    int q = eq[i];
    int prev = atomicExch(&head[q], i);
    node[i] = make_int2(prev, er[i]);
  }
}

// 16 lanes per query; lane l owns channels 8l..8l+7 (one uint4 = 8 bf16)
__global__ __launch_bounds__(256) void k_accum_b(const int* __restrict__ head,
                                                 const int2* __restrict__ node,
                                                 const uint4* __restrict__ featb,
                                                 const float* __restrict__ bxyz,
                                                 float4* __restrict__ accF4,
                                                 float* __restrict__ possum, int M_) {
  int q = blockIdx.x * 16 + (threadIdx.x >> 4);
  int l = threadIdx.x & 15;
  if (q >= M_) return;
  int i = head[q];
  float a0 = 0.f, a1 = 0.f, a2 = 0.f, a3 = 0.f;
  float a4 = 0.f, a5 = 0.f, a6 = 0.f, a7 = 0.f;
  float p = 0.f, c = 0.f;
  while (i >= 0) {
    int2 nd = node[i];              // {next, ref}
    int r = nd.y;
    uint4 v = featb[(size_t)r * 16 + l];
    a0 += bf_lo(v.x); a1 += bf_hi(v.x);
    a2 += bf_lo(v.y); a3 += bf_hi(v.y);
    a4 += bf_lo(v.z); a5 += bf_hi(v.z);
    a6 += bf_lo(v.w); a7 += bf_hi(v.w);
    if (l < 3) p += bxyz[r * 4 + 1 + l];
    c += 1.f;
    i = nd.x;
  }
  float4 o0 = make_float4(a0, a1, a2, a3);
  float4 o1 = make_float4(a4, a5, a6, a7);
  accF4[(size_t)q * 32 + l * 2] = o0;
  accF4[(size_t)q * 32 + l * 2 + 1] = o1;
  if (l < 3) possum[q * 4 + l] = p;
  if (l == 3) possum[q * 4 + 3] = c;
}

// 32 queries x 128 channels per block; 4x4 register microtile per thread.
// sW stride 34 floats: banks = 2c mod 32 -> 16 banks x 2-way (free, m136).
// Epilogue: block-partial per-channel sum/sumsq -> atomicAdd into stats.
__global__ __launch_bounds__(256) void k_gemm(
    const float* __restrict__ accF, const float4* __restrict__ possum4,
    const float* __restrict__ qxyz,
    const float* __restrict__ Wm, const float* __restrict__ Wp,
    const float* __restrict__ bm, const float* __restrict__ bp,
    float* __restrict__ out, float* __restrict__ stats, int M_) {
  __shared__ float sA[32 * 132];   // accF tile [32][128], stride 132
  __shared__ float sW[128 * 34];   // W k-tile [128][32], stride 34
  int t = threadIdx.x;
  int q0 = blockIdx.x * 32;
  #pragma unroll
  for (int i = 0; i < 4; ++i) {
    int f = t + 256 * i;
    int q = f >> 5;
    int kk = (f & 31) << 2;
    float4 v = make_float4(0.f, 0.f, 0.f, 0.f);
    if (q0 + q < M_) v = *(const float4*)&accF[(q0 + q) * 128 + kk];
    *(float4*)&sA[q * 132 + kk] = v;
  }
  float acc[4][4];
  #pragma unroll
  for (int i = 0; i < 4; ++i)
    #pragma unroll
    for (int j = 0; j < 4; ++j) acc[i][j] = 0.f;
  int q0l = (t >> 5) << 2;  // 0,4,...,28
  int cb = t & 31;          // channel base; thread's channels = cb + 32j
  float2* sW2 = (float2*)sW;                    // row stride 17 float2
  const float2* Wm2 = (const float2*)Wm;        // row stride 64 float2
  for (int kt = 0; kt < 4; ++kt) {
    __syncthreads();
    #pragma unroll
    for (int i = 0; i < 8; ++i) {   // stage W[:, kt*32 .. kt*32+31] as float2
      int f = t + 256 * i;          // 2048 float2 slots
      int c = f >> 4;
      int kk2 = f & 15;
      sW2[c * 17 + kk2] = Wm2[c * 64 + kt * 16 + kk2];
    }
    __syncthreads();
    #pragma unroll
    for (int kk4 = 0; kk4 < 8; ++kk4) {
      float4 av[4];
      float2 wa[4], wb[4];
      #pragma unroll
      for (int i = 0; i < 4; ++i)
        av[i] = *(const float4*)&sA[(q0l + i) * 132 + kt * 32 + (kk4 << 2)];
      #pragma unroll
      for (int j = 0; j < 4; ++j) {
        int c = cb + 32 * j;
        wa[j] = sW2[c * 17 + kk4 * 2];
        wb[j] = sW2[c * 17 + kk4 * 2 + 1];
      }
      #pragma unroll
      for (int i = 0; i < 4; ++i)
        #pragma unroll
        for (int j = 0; j < 4; ++j) {
          acc[i][j] = fmaf(av[i].x, wa[j].x, acc[i][j]);
          acc[i][j] = fmaf(av[i].y, wa[j].y, acc[i][j]);
          acc[i][j] = fmaf(av[i].z, wb[j].x, acc[i][j]);
          acc[i][j] = fmaf(av[i].w, wb[j].y, acc[i][j]);
        }
    }
  }
  float fcnt[4], inv[4], dx[4], dy[4], dz[4];
  #pragma unroll
  for (int i = 0; i < 4; ++i) {
    int q = q0 + q0l + i;
    if (q < M_) {
      float4 ps = possum4[q];
      float fc = ps.w;
      fcnt[i] = fc;
      inv[i] = 1.f / fmaxf(fc, 1.f);
      dx[i] = ps.x - fc * qxyz[q * 4 + 1];
      dy[i] = ps.y - fc * qxyz[q * 4 + 2];
      dz[i] = ps.z - fc * qxyz[q * 4 + 3];
    } else {
      fcnt[i] = 0.f; inv[i] = 1.f; dx[i] = dy[i] = dz[i] = 0.f;
    }
  }
  float psum[4], psq[4];
  #pragma unroll
  for (int j = 0; j < 4; ++j) {
    int c = cb + 32 * j;
    float w0 = Wp[c * 3 + 0], w1 = Wp[c * 3 + 1], w2 = Wp[c * 3 + 2];
    float bb = bm[c] + bp[c];
    float s = 0.f, s2 = 0.f;
    #pragma unroll
    for (int i = 0; i < 4; ++i) {
      int q = q0 + q0l + i;
      float v = acc[i][j] + dx[i] * w0 + dy[i] * w1 + dz[i] * w2 + fcnt[i] * bb;
      float val = v * inv[i];
      if (q >= M_) val = 0.f;       // padded rows contribute zero
      if (q < M_) out[q * 128 + c] = val;
      s += val; s2 += val * val;
    }
    psum[j] = s; psq[j] = s2;
  }
  // block reduction of per-channel partials in reused sA space
  __syncthreads();                  // all sA reads done
  float* red = sA;                  // [0..1023]=sum, [1024..2047]=sumsq
  int rg = t >> 5;                  // row-group 0..7
  #pragma unroll
  for (int j = 0; j < 4; ++j) {
    int c = cb + 32 * j;
    red[c * 8 + rg] = psum[j];
    red[1024 + c * 8 + rg] = psq[j];
  }
  __syncthreads();
  if (t < 128) {
    float s = 0.f, s2 = 0.f;
    #pragma unroll
    for (int r = 0; r < 8; ++r) {
      s += red[t * 8 + r];
      s2 += red[1024 + t * 8 + r];
    }
    atomicAdd(&stats[t], s);
    atomicAdd(&stats[128 + t], s2);
  }
}

// inline BN-prep (redundant per block, 128 rsqrt) + normalize + ReLU
__global__ __launch_bounds__(256) void k_bnapply(float* __restrict__ out,
                                                 const float* __restrict__ stats,
                                                 const float* __restrict__ gamma,
                                                 const float* __restrict__ beta,
                                                 float inv_m, int total4) {
  __shared__ float sc[128], sh[128];
  int t = threadIdx.x;
  if (t < 128) {
    float mu = stats[t] * inv_m;
    float var = stats[128 + t] * inv_m - mu * mu;
    var = fmaxf(var, 0.f);
    float s = gamma[t] * rsqrtf(var + 1e-5f);
    sc[t] = s;
    sh[t] = beta[t] - mu * s;
  }
  __syncthreads();
  const float4* sc4 = (const float4*)sc;
  const float4* sh4 = (const float4*)sh;
  float4* o4 = (float4*)out;
  for (int i = blockIdx.x * blockDim.x + t; i < total4;
       i += gridDim.x * blockDim.x) {
    float4 v = o4[i];
    float4 s = sc4[i & 31];
    float4 h = sh4[i & 31];
    v.x = fmaxf(fmaf(v.x, s.x, h.x), 0.f);
    v.y = fmaxf(fmaf(v.y, s.y, h.y), 0.f);
    v.z = fmaxf(fmaf(v.z, s.z, h.z), 0.f);
    v.w = fmaxf(fmaf(v.w, s.w, h.w), 0.f);
    o4[i] = v;
  }
}

static inline size_t align256(size_t x) { return (x + 255) & ~(size_t)255; }

extern "C" void kernel_launch(void* const* d_in, const int* in_sizes, int n_in,
                              void* d_out, int out_size, void* d_ws, size_t ws_size,
                              hipStream_t stream) {
  const float* ref_bxyz   = (const float*)d_in[0];
  const float* ref_feat   = (const float*)d_in[1];
  const float* query_bxyz = (const float*)d_in[2];
  const int*   e_ref      = (const int*)d_in[3];
  const int*   e_query    = (const int*)d_in[4];
  const float* W_pos      = (const float*)d_in[5];
  const float* b_pos      = (const float*)d_in[6];
  const float* W_mlp      = (const float*)d_in[7];
  const float* b_mlp      = (const float*)d_in[8];
  const float* gamma      = (const float*)d_in[9];
  const float* beta       = (const float*)d_in[10];

  int N_ = in_sizes[0] / 4;
  int M_ = in_sizes[2] / 4;
  int E_ = in_sizes[3];

  char* ws = (char*)d_ws;
  size_t off = 0;
  int*   head   = (int*)(ws + off);   off += align256((size_t)M_ * 4);
  int2*  node   = (int2*)(ws + off);  off += align256((size_t)E_ * 8);
  float* possum = (float*)(ws + off); off += align256((size_t)M_ * 4 * 4);
  float* accF   = (float*)(ws + off); off += align256((size_t)M_ * 128 * 4);
  float* stats  = (float*)(ws + off); off += align256(2 * 128 * 4);
  uint4* featb  = (uint4*)(ws + off);

  hipMemsetAsync(head, 0xFF, (size_t)M_ * 4, stream);     // head[q] = -1
  hipMemsetAsync(stats, 0, 2 * 128 * 4, stream);

  float* out = (float*)d_out;
  int n8 = N_ * 16;                 // uint4 groups (8 floats each)
  int nwork = (E_ > n8) ? E_ : n8;

  k_build_cvt<<<(nwork + 255) / 256, 256, 0, stream>>>(
      e_query, e_ref, head, node, (const float4*)ref_feat, featb, E_, n8);
  k_accum_b<<<(M_ + 15) / 16, 256, 0, stream>>>(head, node, featb, ref_bxyz,
                                                (float4*)accF, possum, M_);
  k_gemm<<<(M_ + 31) / 32, 256, 0, stream>>>(accF, (const float4*)possum, query_bxyz,
                                             W_mlp, W_pos, b_mlp, b_pos, out, stats, M_);
  k_bnapply<<<2048, 256, 0, stream>>>(out, stats, gamma, beta, 1.f / (float)M_,
                                      M_ * 32);
}